// Round 1
// baseline (1316.846 us; speedup 1.0000x reference)
//
#include <hip/hip_runtime.h>
#include <hip/hip_bf16.h>

#define NROWS 8192
#define EMB   512
#define NCLS  98
#define ALPHA_F 10.0f
#define BETA_F  2.0f

#define BM 64
#define BN 64
#define BK 32
#define LDA 68   // padded LDS stride (68*4 bytes = 272, 16B-aligned rows)

// ---------------- class histogram ----------------
__global__ void hist_kernel(const int* __restrict__ t, int* __restrict__ hist) {
    int i = blockIdx.x * blockDim.x + threadIdx.x;
    if (i < NROWS) atomicAdd(&hist[t[i]], 1);
}

// ---------------- kernel column inverse norms ----------------
__global__ void colnorm_kernel(const float* __restrict__ K, float* __restrict__ colinv) {
    int c = blockIdx.x;            // 0..97
    float s = 0.f;
    for (int k = threadIdx.x; k < EMB; k += 64) {
        float v = K[k * NCLS + c];
        s = fmaf(v, v, s);
    }
    #pragma unroll
    for (int off = 32; off > 0; off >>= 1) s += __shfl_down(s, off);
    if (threadIdx.x == 0) colinv[c] = 1.0f / sqrtf(s);
}

// ---------------- big one: sim = X X^T, reduced to per-row sums ----------------
__global__ __launch_bounds__(256) void simred_kernel(
        const float* __restrict__ X, const int* __restrict__ T,
        float* __restrict__ S, float* __restrict__ SAME) {
    __shared__ float As[BK * LDA];
    __shared__ float Bs[BK * LDA];
    __shared__ int   trow[BM], tcol[BN];
    __shared__ float redS[BM], redSame[BM];

    const int tid = threadIdx.x;
    const int tx = tid & 15, ty = tid >> 4;
    const int i0 = blockIdx.x * BM, j0 = blockIdx.y * BN;

    if (tid < BM) {
        trow[tid] = T[i0 + tid];
        tcol[tid] = T[j0 + tid];
        redS[tid] = 0.f;
        redSame[tid] = 0.f;
    }

    float c[4][4] = {};
    for (int kk = 0; kk < EMB; kk += BK) {
        #pragma unroll
        for (int q = 0; q < 2; ++q) {
            int l  = tid * 2 + q;        // 0..511
            int r  = l >> 3;             // 0..63
            int kq = (l & 7) << 2;       // 0,4,...,28
            const float4 va = *(const float4*)(X + (size_t)(i0 + r) * EMB + kk + kq);
            As[(kq + 0) * LDA + r] = va.x;
            As[(kq + 1) * LDA + r] = va.y;
            As[(kq + 2) * LDA + r] = va.z;
            As[(kq + 3) * LDA + r] = va.w;
            const float4 vb = *(const float4*)(X + (size_t)(j0 + r) * EMB + kk + kq);
            Bs[(kq + 0) * LDA + r] = vb.x;
            Bs[(kq + 1) * LDA + r] = vb.y;
            Bs[(kq + 2) * LDA + r] = vb.z;
            Bs[(kq + 3) * LDA + r] = vb.w;
        }
        __syncthreads();
        #pragma unroll
        for (int k = 0; k < BK; ++k) {
            float4 a4 = *(const float4*)&As[k * LDA + ty * 4];
            float4 b4 = *(const float4*)&Bs[k * LDA + tx * 4];
            float a[4] = {a4.x, a4.y, a4.z, a4.w};
            float b[4] = {b4.x, b4.y, b4.z, b4.w};
            #pragma unroll
            for (int i = 0; i < 4; ++i)
                #pragma unroll
                for (int j = 0; j < 4; ++j)
                    c[i][j] = fmaf(a[i], b[j], c[i][j]);
        }
        __syncthreads();
    }

    // per-thread reduce of its 4x4 into per-row partials
    #pragma unroll
    for (int i = 0; i < 4; ++i) {
        int r = ty * 4 + i;
        int tr = trow[r];
        float s = 0.f, sm = 0.f;
        #pragma unroll
        for (int j = 0; j < 4; ++j) {
            float v = c[i][j];
            s += v;
            if (tcol[tx * 4 + j] == tr) sm += v;
        }
        atomicAdd(&redS[r], s);
        atomicAdd(&redSame[r], sm);
    }
    __syncthreads();
    if (tid < BM) {
        atomicAdd(&S[i0 + tid],    redS[tid]);
        atomicAdd(&SAME[i0 + tid], redSame[tid]);
    }
}

// ---------------- loss + precision (one block per row) ----------------
__global__ __launch_bounds__(128) void loss_kernel(
        const float* __restrict__ X, const int* __restrict__ T,
        const float* __restrict__ K, const float* __restrict__ colinv,
        double* __restrict__ acc) {
    const int row = blockIdx.x;
    const int tid = threadIdx.x;
    __shared__ float xs[EMB];
    *(float4*)&xs[tid * 4] = *(const float4*)&X[(size_t)row * EMB + tid * 4];
    __syncthreads();

    const int tgt = T[row];
    const int c = tid;
    float logit = -1e30f;
    if (c < NCLS) {
        float d = 0.f;
        #pragma unroll 4
        for (int k = 0; k < EMB; ++k) d = fmaf(K[k * NCLS + c], xs[k], d);
        float cosv = d * colinv[c];
        cosv = fminf(1.f, fmaxf(-1.f, cosv));
        logit = (cosv - (c == tgt ? BETA_F : 0.f)) * ALPHA_F;
    }

    __shared__ float rv[128];
    __shared__ int   ri[128];
    __shared__ float Lt;
    if (c == tgt) Lt = logit;

    // max reduce
    rv[tid] = logit;
    __syncthreads();
    #pragma unroll
    for (int s = 64; s > 0; s >>= 1) {
        if (tid < s) rv[tid] = fmaxf(rv[tid], rv[tid + s]);
        __syncthreads();
    }
    const float m = rv[0];
    __syncthreads();

    // sum-exp reduce
    rv[tid] = (c < NCLS) ? expf(logit - m) : 0.f;
    __syncthreads();
    #pragma unroll
    for (int s = 64; s > 0; s >>= 1) {
        if (tid < s) rv[tid] += rv[tid + s];
        __syncthreads();
    }
    const float lse = m + logf(rv[0]);
    __syncthreads();

    // argmax reduce (first-index tie break, matches jnp.argmax)
    rv[tid] = logit;
    ri[tid] = (c < NCLS) ? c : 0x7fffffff;
    __syncthreads();
    #pragma unroll
    for (int s = 64; s > 0; s >>= 1) {
        if (tid < s) {
            float vo = rv[tid + s]; int io = ri[tid + s];
            if (vo > rv[tid] || (vo == rv[tid] && io < ri[tid])) { rv[tid] = vo; ri[tid] = io; }
        }
        __syncthreads();
    }

    if (tid == 0) {
        float loss_i = lse - Lt;
        atomicAdd(&acc[0], (double)loss_i);
        atomicAdd(&acc[1], (ri[0] == tgt) ? 1.0 : 0.0);
    }
}

// ---------------- per-row finalize: pos/neg means ----------------
__global__ void finalize_kernel(
        const float* __restrict__ X, const int* __restrict__ T,
        const int* __restrict__ hist, const float* __restrict__ S,
        const float* __restrict__ SAME, double* __restrict__ acc) {
    int r = blockIdx.x * blockDim.x + threadIdx.x;
    if (r >= NROWS) return;
    const float* x = X + (size_t)r * EMB;
    double d = 0.0;
    for (int k = 0; k < EMB; ++k) d = fma((double)x[k], (double)x[k], d);
    int h = hist[T[r]];
    float same = SAME[r];
    float pos_sum; int pos_cnt;
    if (d < 1.0) {              // reference keeps the diagonal in this case
        pos_sum = same;         // our accumulated diag ~= d, keep it
        pos_cnt = h;
    } else {                    // reference drops the diagonal
        pos_sum = same - (float)d;
        pos_cnt = h - 1;
    }
    float neg_sum = S[r] - same;
    int   neg_cnt = NROWS - h;
    atomicAdd(&acc[2], (double)(pos_sum / (float)pos_cnt));
    atomicAdd(&acc[3], (double)(neg_sum / (float)neg_cnt));
}

__global__ void out_kernel(const double* __restrict__ acc, float* __restrict__ out) {
    if (threadIdx.x == 0) {
        out[0] = (float)(acc[0] / NROWS);
        out[1] = (float)(acc[1] / NROWS);
        out[2] = (float)(acc[2] / NROWS);
        out[3] = (float)(acc[3] / NROWS);
    }
}

extern "C" void kernel_launch(void* const* d_in, const int* in_sizes, int n_in,
                              void* d_out, int out_size, void* d_ws, size_t ws_size,
                              hipStream_t stream) {
    const float* X = (const float*)d_in[0];   // [8192, 512]
    const int*   T = (const int*)d_in[1];     // [8192]
    const float* K = (const float*)d_in[2];   // [512, 98]
    float* out = (float*)d_out;               // 4 scalars

    double* acc    = (double*)d_ws;           // 4 doubles
    int*    hist   = (int*)(acc + 4);         // 98
    float*  colinv = (float*)(hist + NCLS);   // 98
    float*  S      = colinv + NCLS;           // 8192
    float*  SAME   = S + NROWS;               // 8192

    size_t zero_bytes = sizeof(double) * 4 + sizeof(int) * NCLS
                      + sizeof(float) * (NCLS + 2 * NROWS);
    hipMemsetAsync(d_ws, 0, zero_bytes, stream);

    hist_kernel<<<(NROWS + 255) / 256, 256, 0, stream>>>(T, hist);
    colnorm_kernel<<<NCLS, 64, 0, stream>>>(K, colinv);
    simred_kernel<<<dim3(NROWS / BM, NROWS / BN), 256, 0, stream>>>(X, T, S, SAME);
    loss_kernel<<<NROWS, 128, 0, stream>>>(X, T, K, colinv, acc);
    finalize_kernel<<<(NROWS + 255) / 256, 256, 0, stream>>>(X, T, hist, S, SAME, acc);
    out_kernel<<<1, 64, 0, stream>>>(acc, out);
}

// Round 2
// 430.796 us; speedup vs baseline: 3.0568x; 3.0568x over previous
//
#include <hip/hip_runtime.h>
#include <hip/hip_bf16.h>

typedef __attribute__((ext_vector_type(8))) short bf16x8;
typedef __attribute__((ext_vector_type(4))) float f32x4;

#define NROWS 8192
#define EMB   512
#define NCLS  98
#define ALPHA_F 10.0f
#define BETA_F  2.0f

// ---------------- class histogram ----------------
__global__ void hist_kernel(const int* __restrict__ t, int* __restrict__ hist) {
    int i = blockIdx.x * blockDim.x + threadIdx.x;
    if (i < NROWS) atomicAdd(&hist[t[i]], 1);
}

// ---------------- kernel column inverse norms ----------------
__global__ void colnorm_kernel(const float* __restrict__ K, float* __restrict__ colinv) {
    int c = blockIdx.x;            // 0..97
    float s = 0.f;
    for (int k = threadIdx.x; k < EMB; k += 64) {
        float v = K[k * NCLS + c];
        s = fmaf(v, v, s);
    }
    #pragma unroll
    for (int off = 32; off > 0; off >>= 1) s += __shfl_down(s, off);
    if (threadIdx.x == 0) colinv[c] = 1.0f / sqrtf(s);
}

// ---------------- X -> bf16 (RNE) ----------------
__global__ __launch_bounds__(256) void tobf16_kernel(const float* __restrict__ X,
                                                     unsigned short* __restrict__ Xb) {
    int i = blockIdx.x * 256 + threadIdx.x;    // each handles 8 floats
    const float4* Xv = (const float4*)X;
    float4 a = Xv[(size_t)i * 2], b = Xv[(size_t)i * 2 + 1];
    float v[8] = {a.x, a.y, a.z, a.w, b.x, b.y, b.z, b.w};
    bf16x8 o;
    #pragma unroll
    for (int j = 0; j < 8; ++j) {
        unsigned u = __builtin_bit_cast(unsigned, v[j]);
        u += 0x7FFF + ((u >> 16) & 1);          // round-to-nearest-even
        o[j] = (short)(u >> 16);
    }
    *(bf16x8*)(Xb + (size_t)i * 8) = o;
}

// ---------------- bf16 MFMA sim = Xb Xb^T, reduced to per-row sums ----------------
#define TBM 128
#define TBN 128
#define TBK 64

__device__ __forceinline__ void g2l16(const void* g, void* l) {
    __builtin_amdgcn_global_load_lds(
        (const __attribute__((address_space(1))) unsigned int*)g,
        (__attribute__((address_space(3))) unsigned int*)l, 16, 0, 0);
}

__global__ __launch_bounds__(256) void simred_mfma(
        const unsigned short* __restrict__ Xb, const int* __restrict__ T,
        float* __restrict__ S, float* __restrict__ SAME) {
    __shared__ unsigned short As[TBM * TBK];   // [128][64] bf16, row-major
    __shared__ unsigned short Bs[TBN * TBK];
    __shared__ float redS[TBM], redSame[TBM];

    const int tid = threadIdx.x;
    const int wid = tid >> 6, lane = tid & 63;
    const int wr = wid >> 1, wc = wid & 1;     // 2x2 waves, 64x64 each
    const int i0 = blockIdx.x * TBM, j0 = blockIdx.y * TBN;

    if (tid < TBM) { redS[tid] = 0.f; redSame[tid] = 0.f; }

    f32x4 acc[4][4] = {};
    const char* Xbytes = (const char*)Xb;

    for (int kk = 0; kk < EMB; kk += TBK) {
        // stage A and B tiles: per lane 16B, linear LDS dest (matches HW base+lane*16)
        #pragma unroll
        for (int q = 0; q < 4; ++q) {
            int lb = wid * 4096 + q * 1024 + lane * 16;  // byte offset in tile
            int row = lb >> 7, colb = lb & 127;          // 128 B per row (64 bf16)
            g2l16(Xbytes + (((size_t)(i0 + row)) << 10) + (kk << 1) + colb, (char*)As + lb);
            g2l16(Xbytes + (((size_t)(j0 + row)) << 10) + (kk << 1) + colb, (char*)Bs + lb);
        }
        __syncthreads();   // drains vmcnt before barrier (compiler-emitted)

        #pragma unroll
        for (int ks = 0; ks < 2; ++ks) {
            bf16x8 a[4], b[4];
            #pragma unroll
            for (int mi = 0; mi < 4; ++mi)
                a[mi] = *(const bf16x8*)&As[(wr * 64 + mi * 16 + (lane & 15)) * TBK + ks * 32 + (lane >> 4) * 8];
            #pragma unroll
            for (int ni = 0; ni < 4; ++ni)
                b[ni] = *(const bf16x8*)&Bs[(wc * 64 + ni * 16 + (lane & 15)) * TBK + ks * 32 + (lane >> 4) * 8];
            #pragma unroll
            for (int mi = 0; mi < 4; ++mi)
                #pragma unroll
                for (int ni = 0; ni < 4; ++ni)
                    acc[mi][ni] = __builtin_amdgcn_mfma_f32_16x16x32_bf16(a[mi], b[ni], acc[mi][ni], 0, 0, 0);
        }
        __syncthreads();
    }

    // reduce 64x64 wave tile to per-row sums (C map: col=lane&15, row=(lane>>4)*4+reg)
    int ccls[4];
    #pragma unroll
    for (int ni = 0; ni < 4; ++ni) ccls[ni] = T[j0 + wc * 64 + ni * 16 + (lane & 15)];
    const int g = lane >> 4;
    #pragma unroll
    for (int mi = 0; mi < 4; ++mi) {
        #pragma unroll
        for (int r = 0; r < 4; ++r) {
            int rowl = wr * 64 + mi * 16 + g * 4 + r;
            int rc = T[i0 + rowl];
            float s = 0.f, sm = 0.f;
            #pragma unroll
            for (int ni = 0; ni < 4; ++ni) {
                float v = acc[mi][ni][r];
                s += v;
                if (ccls[ni] == rc) sm += v;
            }
            #pragma unroll
            for (int m = 1; m < 16; m <<= 1) { s += __shfl_xor(s, m); sm += __shfl_xor(sm, m); }
            if ((lane & 15) == 0) { atomicAdd(&redS[rowl], s); atomicAdd(&redSame[rowl], sm); }
        }
    }
    __syncthreads();
    if (tid < TBM) {
        atomicAdd(&S[i0 + tid], redS[tid]);
        atomicAdd(&SAME[i0 + tid], redSame[tid]);
    }
}

// ---------------- fallback f32 simred (if workspace too small for Xb) ----------------
#define BM 64
#define BN 64
#define BK 32
#define LDA 68

__global__ __launch_bounds__(256) void simred_kernel(
        const float* __restrict__ X, const int* __restrict__ T,
        float* __restrict__ S, float* __restrict__ SAME) {
    __shared__ float As[BK * LDA];
    __shared__ float Bs[BK * LDA];
    __shared__ int   trow[BM], tcol[BN];
    __shared__ float redS[BM], redSame[BM];

    const int tid = threadIdx.x;
    const int tx = tid & 15, ty = tid >> 4;
    const int i0 = blockIdx.x * BM, j0 = blockIdx.y * BN;

    if (tid < BM) {
        trow[tid] = T[i0 + tid];
        tcol[tid] = T[j0 + tid];
        redS[tid] = 0.f;
        redSame[tid] = 0.f;
    }

    float c[4][4] = {};
    for (int kk = 0; kk < EMB; kk += BK) {
        #pragma unroll
        for (int q = 0; q < 2; ++q) {
            int l  = tid * 2 + q;
            int r  = l >> 3;
            int kq = (l & 7) << 2;
            const float4 va = *(const float4*)(X + (size_t)(i0 + r) * EMB + kk + kq);
            As[(kq + 0) * LDA + r] = va.x;
            As[(kq + 1) * LDA + r] = va.y;
            As[(kq + 2) * LDA + r] = va.z;
            As[(kq + 3) * LDA + r] = va.w;
            const float4 vb = *(const float4*)(X + (size_t)(j0 + r) * EMB + kk + kq);
            Bs[(kq + 0) * LDA + r] = vb.x;
            Bs[(kq + 1) * LDA + r] = vb.y;
            Bs[(kq + 2) * LDA + r] = vb.z;
            Bs[(kq + 3) * LDA + r] = vb.w;
        }
        __syncthreads();
        #pragma unroll
        for (int k = 0; k < BK; ++k) {
            float4 a4 = *(const float4*)&As[k * LDA + ty * 4];
            float4 b4 = *(const float4*)&Bs[k * LDA + tx * 4];
            float a[4] = {a4.x, a4.y, a4.z, a4.w};
            float b[4] = {b4.x, b4.y, b4.z, b4.w};
            #pragma unroll
            for (int i = 0; i < 4; ++i)
                #pragma unroll
                for (int j = 0; j < 4; ++j)
                    c[i][j] = fmaf(a[i], b[j], c[i][j]);
        }
        __syncthreads();
    }

    #pragma unroll
    for (int i = 0; i < 4; ++i) {
        int r = ty * 4 + i;
        int tr = trow[r];
        float s = 0.f, sm = 0.f;
        #pragma unroll
        for (int j = 0; j < 4; ++j) {
            float v = c[i][j];
            s += v;
            if (tcol[tx * 4 + j] == tr) sm += v;
        }
        atomicAdd(&redS[r], s);
        atomicAdd(&redSame[r], sm);
    }
    __syncthreads();
    if (tid < BM) {
        atomicAdd(&S[i0 + tid],    redS[tid]);
        atomicAdd(&SAME[i0 + tid], redSame[tid]);
    }
}

// ---------------- loss + precision (one block per row) ----------------
__global__ __launch_bounds__(128) void loss_kernel(
        const float* __restrict__ X, const int* __restrict__ T,
        const float* __restrict__ K, const float* __restrict__ colinv,
        double* __restrict__ acc) {
    const int row = blockIdx.x;
    const int tid = threadIdx.x;
    __shared__ float xs[EMB];
    *(float4*)&xs[tid * 4] = *(const float4*)&X[(size_t)row * EMB + tid * 4];
    __syncthreads();

    const int tgt = T[row];
    const int c = tid;
    float logit = -1e30f;
    if (c < NCLS) {
        float d = 0.f;
        #pragma unroll 4
        for (int k = 0; k < EMB; ++k) d = fmaf(K[k * NCLS + c], xs[k], d);
        float cosv = d * colinv[c];
        cosv = fminf(1.f, fmaxf(-1.f, cosv));
        logit = (cosv - (c == tgt ? BETA_F : 0.f)) * ALPHA_F;
    }

    __shared__ float rv[128];
    __shared__ int   ri[128];
    __shared__ float Lt;
    if (c == tgt) Lt = logit;

    rv[tid] = logit;
    __syncthreads();
    #pragma unroll
    for (int s = 64; s > 0; s >>= 1) {
        if (tid < s) rv[tid] = fmaxf(rv[tid], rv[tid + s]);
        __syncthreads();
    }
    const float m = rv[0];
    __syncthreads();

    rv[tid] = (c < NCLS) ? expf(logit - m) : 0.f;
    __syncthreads();
    #pragma unroll
    for (int s = 64; s > 0; s >>= 1) {
        if (tid < s) rv[tid] += rv[tid + s];
        __syncthreads();
    }
    const float lse = m + logf(rv[0]);
    __syncthreads();

    rv[tid] = logit;
    ri[tid] = (c < NCLS) ? c : 0x7fffffff;
    __syncthreads();
    #pragma unroll
    for (int s = 64; s > 0; s >>= 1) {
        if (tid < s) {
            float vo = rv[tid + s]; int io = ri[tid + s];
            if (vo > rv[tid] || (vo == rv[tid] && io < ri[tid])) { rv[tid] = vo; ri[tid] = io; }
        }
        __syncthreads();
    }

    if (tid == 0) {
        float loss_i = lse - Lt;
        atomicAdd(&acc[0], (double)loss_i);
        atomicAdd(&acc[1], (ri[0] == tgt) ? 1.0 : 0.0);
    }
}

// ---------------- per-row finalize: pos/neg means ----------------
__global__ void finalize_kernel(
        const float* __restrict__ X, const int* __restrict__ T,
        const int* __restrict__ hist, const float* __restrict__ S,
        const float* __restrict__ SAME, double* __restrict__ acc) {
    int r = blockIdx.x * blockDim.x + threadIdx.x;
    if (r >= NROWS) return;
    const float* x = X + (size_t)r * EMB;
    double d = 0.0;
    for (int k = 0; k < EMB; ++k) d = fma((double)x[k], (double)x[k], d);
    int h = hist[T[r]];
    float same = SAME[r];
    float pos_sum; int pos_cnt;
    if (d < 1.0) {
        pos_sum = same;
        pos_cnt = h;
    } else {
        pos_sum = same - (float)d;
        pos_cnt = h - 1;
    }
    float neg_sum = S[r] - same;
    int   neg_cnt = NROWS - h;
    atomicAdd(&acc[2], (double)(pos_sum / (float)pos_cnt));
    atomicAdd(&acc[3], (double)(neg_sum / (float)neg_cnt));
}

__global__ void out_kernel(const double* __restrict__ acc, float* __restrict__ out) {
    if (threadIdx.x == 0) {
        out[0] = (float)(acc[0] / NROWS);
        out[1] = (float)(acc[1] / NROWS);
        out[2] = (float)(acc[2] / NROWS);
        out[3] = (float)(acc[3] / NROWS);
    }
}

extern "C" void kernel_launch(void* const* d_in, const int* in_sizes, int n_in,
                              void* d_out, int out_size, void* d_ws, size_t ws_size,
                              hipStream_t stream) {
    const float* X = (const float*)d_in[0];   // [8192, 512]
    const int*   T = (const int*)d_in[1];     // [8192]
    const float* K = (const float*)d_in[2];   // [512, 98]
    float* out = (float*)d_out;               // 4 scalars

    const size_t XB_BYTES = (size_t)NROWS * EMB * sizeof(unsigned short); // 8 MB
    const size_t MISC_BYTES = sizeof(double) * 4 + sizeof(int) * NCLS
                            + sizeof(float) * (NCLS + 2 * NROWS);

    if (ws_size >= XB_BYTES + MISC_BYTES + 256) {
        // fast path: bf16 MFMA
        unsigned short* Xb = (unsigned short*)d_ws;
        char* misc = (char*)d_ws + XB_BYTES;
        double* acc    = (double*)misc;
        int*    hist   = (int*)(acc + 4);
        float*  colinv = (float*)(hist + NCLS);
        float*  S      = colinv + NCLS;
        float*  SAME   = S + NROWS;

        hipMemsetAsync(misc, 0, MISC_BYTES, stream);
        tobf16_kernel<<<(NROWS * EMB / 8 + 255) / 256, 256, 0, stream>>>(X, Xb);
        hist_kernel<<<(NROWS + 255) / 256, 256, 0, stream>>>(T, hist);
        colnorm_kernel<<<NCLS, 64, 0, stream>>>(K, colinv);
        simred_mfma<<<dim3(NROWS / TBM, NROWS / TBN), 256, 0, stream>>>(Xb, T, S, SAME);
        loss_kernel<<<NROWS, 128, 0, stream>>>(X, T, K, colinv, acc);
        finalize_kernel<<<(NROWS + 255) / 256, 256, 0, stream>>>(X, T, hist, S, SAME, acc);
        out_kernel<<<1, 64, 0, stream>>>(acc, out);
    } else {
        // fallback: f32 path
        double* acc    = (double*)d_ws;
        int*    hist   = (int*)(acc + 4);
        float*  colinv = (float*)(hist + NCLS);
        float*  S      = colinv + NCLS;
        float*  SAME   = S + NROWS;

        hipMemsetAsync(d_ws, 0, MISC_BYTES, stream);
        hist_kernel<<<(NROWS + 255) / 256, 256, 0, stream>>>(T, hist);
        colnorm_kernel<<<NCLS, 64, 0, stream>>>(K, colinv);
        simred_kernel<<<dim3(NROWS / BM, NROWS / BN), 256, 0, stream>>>(X, T, S, SAME);
        loss_kernel<<<NROWS, 128, 0, stream>>>(X, T, K, colinv, acc);
        finalize_kernel<<<(NROWS + 255) / 256, 256, 0, stream>>>(X, T, hist, S, SAME, acc);
        out_kernel<<<1, 64, 0, stream>>>(acc, out);
    }
}

// Round 3
// 208.637 us; speedup vs baseline: 6.3117x; 2.0648x over previous
//
#include <hip/hip_runtime.h>
#include <hip/hip_bf16.h>

typedef __attribute__((ext_vector_type(8))) short bf16x8;
typedef __attribute__((ext_vector_type(4))) float f32x4;

#define NROWS 8192
#define EMB   512
#define NCLS  98
#define NCPAD 128
#define ALPHA_F 10.0f
#define BETA_F  2.0f

__device__ __forceinline__ unsigned short f2bf(float x) {
    unsigned u = __builtin_bit_cast(unsigned, x);
    u += 0x7FFF + ((u >> 16) & 1);
    return (unsigned short)(u >> 16);
}

// ---------------- class histogram ----------------
__global__ void hist_kernel(const int* __restrict__ t, int* __restrict__ hist) {
    int i = blockIdx.x * blockDim.x + threadIdx.x;
    if (i < NROWS) atomicAdd(&hist[t[i]], 1);
}

// ---------------- kernel column inverse norms (fallback path only) ----------------
__global__ void colnorm_kernel(const float* __restrict__ K, float* __restrict__ colinv) {
    int c = blockIdx.x;
    float s = 0.f;
    for (int k = threadIdx.x; k < EMB; k += 64) {
        float v = K[k * NCLS + c];
        s = fmaf(v, v, s);
    }
    #pragma unroll
    for (int off = 32; off > 0; off >>= 1) s += __shfl_down(s, off);
    if (threadIdx.x == 0) colinv[c] = 1.0f / sqrtf(s);
}

// ---------------- X -> bf16 (RNE) ----------------
__global__ __launch_bounds__(256) void tobf16_kernel(const float* __restrict__ X,
                                                     unsigned short* __restrict__ Xb) {
    int i = blockIdx.x * 256 + threadIdx.x;
    const float4* Xv = (const float4*)X;
    float4 a = Xv[(size_t)i * 2], b = Xv[(size_t)i * 2 + 1];
    float v[8] = {a.x, a.y, a.z, a.w, b.x, b.y, b.z, b.w};
    bf16x8 o;
    #pragma unroll
    for (int j = 0; j < 8; ++j) o[j] = (short)f2bf(v[j]);
    *(bf16x8*)(Xb + (size_t)i * 8) = o;
}

// ---------------- KbT[c][k] = bf16( K[k][c] / ||K[:,c]|| ), c in [0,128) padded ----------------
__global__ __launch_bounds__(64) void kprep_kernel(const float* __restrict__ K,
                                                   unsigned short* __restrict__ KbT) {
    int c = blockIdx.x;      // 0..127
    int t = threadIdx.x;     // 0..63
    if (c < NCLS) {
        float v[8]; float s = 0.f;
        #pragma unroll
        for (int q = 0; q < 8; ++q) {
            float x = K[(size_t)(t + q * 64) * NCLS + c];
            v[q] = x; s = fmaf(x, x, s);
        }
        #pragma unroll
        for (int d = 32; d > 0; d >>= 1) s += __shfl_xor(s, d);
        float inv = 1.0f / sqrtf(s);
        #pragma unroll
        for (int q = 0; q < 8; ++q)
            KbT[(size_t)c * EMB + t + q * 64] = f2bf(v[q] * inv);
    } else {
        #pragma unroll
        for (int q = 0; q < 8; ++q)
            KbT[(size_t)c * EMB + t + q * 64] = 0;
    }
}

// ---------------- bf16 MFMA sim = Xb Xb^T, reduced to per-row sums ----------------
#define TBM 128
#define TBN 128
#define TBK 64

__device__ __forceinline__ void g2l16(const void* g, void* l) {
    __builtin_amdgcn_global_load_lds(
        (const __attribute__((address_space(1))) unsigned int*)g,
        (__attribute__((address_space(3))) unsigned int*)l, 16, 0, 0);
}

__global__ __launch_bounds__(256) void simred_mfma(
        const unsigned short* __restrict__ Xb, const int* __restrict__ T,
        float* __restrict__ S, float* __restrict__ SAME) {
    __shared__ unsigned short As[TBM * TBK];
    __shared__ unsigned short Bs[TBN * TBK];
    __shared__ float redS[TBM], redSame[TBM];

    const int tid = threadIdx.x;
    const int wid = tid >> 6, lane = tid & 63;
    const int wr = wid >> 1, wc = wid & 1;
    const int i0 = blockIdx.x * TBM, j0 = blockIdx.y * TBN;

    if (tid < TBM) { redS[tid] = 0.f; redSame[tid] = 0.f; }

    f32x4 acc[4][4] = {};
    const char* Xbytes = (const char*)Xb;

    for (int kk = 0; kk < EMB; kk += TBK) {
        #pragma unroll
        for (int q = 0; q < 4; ++q) {
            int lb = wid * 4096 + q * 1024 + lane * 16;
            int row = lb >> 7, colb = lb & 127;
            g2l16(Xbytes + (((size_t)(i0 + row)) << 10) + (kk << 1) + colb, (char*)As + lb);
            g2l16(Xbytes + (((size_t)(j0 + row)) << 10) + (kk << 1) + colb, (char*)Bs + lb);
        }
        __syncthreads();

        #pragma unroll
        for (int ks = 0; ks < 2; ++ks) {
            bf16x8 a[4], b[4];
            #pragma unroll
            for (int mi = 0; mi < 4; ++mi)
                a[mi] = *(const bf16x8*)&As[(wr * 64 + mi * 16 + (lane & 15)) * TBK + ks * 32 + (lane >> 4) * 8];
            #pragma unroll
            for (int ni = 0; ni < 4; ++ni)
                b[ni] = *(const bf16x8*)&Bs[(wc * 64 + ni * 16 + (lane & 15)) * TBK + ks * 32 + (lane >> 4) * 8];
            #pragma unroll
            for (int mi = 0; mi < 4; ++mi)
                #pragma unroll
                for (int ni = 0; ni < 4; ++ni)
                    acc[mi][ni] = __builtin_amdgcn_mfma_f32_16x16x32_bf16(a[mi], b[ni], acc[mi][ni], 0, 0, 0);
        }
        __syncthreads();
    }

    int ccls[4];
    #pragma unroll
    for (int ni = 0; ni < 4; ++ni) ccls[ni] = T[j0 + wc * 64 + ni * 16 + (lane & 15)];
    const int g = lane >> 4;
    #pragma unroll
    for (int mi = 0; mi < 4; ++mi) {
        #pragma unroll
        for (int r = 0; r < 4; ++r) {
            int rowl = wr * 64 + mi * 16 + g * 4 + r;
            int rc = T[i0 + rowl];
            float s = 0.f, sm = 0.f;
            #pragma unroll
            for (int ni = 0; ni < 4; ++ni) {
                float v = acc[mi][ni][r];
                s += v;
                if (ccls[ni] == rc) sm += v;
            }
            #pragma unroll
            for (int m = 1; m < 16; m <<= 1) { s += __shfl_xor(s, m); sm += __shfl_xor(sm, m); }
            if ((lane & 15) == 0) { atomicAdd(&redS[rowl], s); atomicAdd(&redSame[rowl], sm); }
        }
    }
    __syncthreads();
    if (tid < TBM) {
        atomicAdd(&S[i0 + tid], redS[tid]);
        atomicAdd(&SAME[i0 + tid], redSame[tid]);
    }
}

// ---------------- MFMA logits + in-register softmax/argmax/loss ----------------
// one wave per 16 rows; 128 padded class cols; KbT is [128][512] bf16 row-major
__global__ __launch_bounds__(64) void logits_kernel(
        const unsigned short* __restrict__ Xb, const unsigned short* __restrict__ KbT,
        const int* __restrict__ T, double* __restrict__ acc) {
    const int row0 = blockIdx.x * 16;
    const int lane = threadIdx.x;
    const int c0 = lane & 15, g = lane >> 4;

    f32x4 av[8] = {};
    for (int kk = 0; kk < EMB; kk += 32) {
        bf16x8 a = *(const bf16x8*)&Xb[(size_t)(row0 + c0) * EMB + kk + g * 8];
        #pragma unroll
        for (int f = 0; f < 8; ++f) {
            bf16x8 b = *(const bf16x8*)&KbT[(size_t)(f * 16 + c0) * EMB + kk + g * 8];
            av[f] = __builtin_amdgcn_mfma_f32_16x16x32_bf16(a, b, av[f], 0, 0, 0);
        }
    }

    float lossacc = 0.f, pracc = 0.f;
    #pragma unroll
    for (int r = 0; r < 4; ++r) {
        const int row = row0 + g * 4 + r;
        const int tgt = T[row];
        float vals[8];
        float m = -1e30f;
        #pragma unroll
        for (int f = 0; f < 8; ++f) {
            int col = f * 16 + c0;
            float cosv = fminf(1.f, fmaxf(-1.f, av[f][r]));
            float logit = (cosv - (col == tgt ? BETA_F : 0.f)) * ALPHA_F;
            if (col >= NCLS) logit = -1e30f;
            vals[f] = logit;
            m = fmaxf(m, logit);
        }
        #pragma unroll
        for (int d = 1; d < 16; d <<= 1) m = fmaxf(m, __shfl_xor(m, d));

        float se = 0.f, tval = -1e30f;
        float bv = -1e30f; int bi = 0x7fffffff;
        #pragma unroll
        for (int f = 0; f < 8; ++f) {
            int col = f * 16 + c0;
            se += __expf(vals[f] - m) * (col < NCLS ? 1.f : 0.f);
            if (col == tgt) tval = vals[f];
            if (vals[f] > bv) { bv = vals[f]; bi = col; }
        }
        #pragma unroll
        for (int d = 1; d < 16; d <<= 1) {
            se += __shfl_xor(se, d);
            tval = fmaxf(tval, __shfl_xor(tval, d));
            float ov = __shfl_xor(bv, d); int oi = __shfl_xor(bi, d);
            if (ov > bv || (ov == bv && oi < bi)) { bv = ov; bi = oi; }
        }
        if (c0 == 0) {
            lossacc += (m + logf(se)) - tval;
            pracc += (bi == tgt) ? 1.f : 0.f;
        }
    }
    // sum lanes 0,16,32,48 (c0==0 preserved under xor 16/32)
    lossacc += __shfl_xor(lossacc, 16); lossacc += __shfl_xor(lossacc, 32);
    pracc   += __shfl_xor(pracc, 16);   pracc   += __shfl_xor(pracc, 32);
    if (lane == 0) {
        atomicAdd(&acc[0], (double)lossacc);
        atomicAdd(&acc[1], (double)pracc);
    }
}

// ---------------- fallback f32 simred ----------------
#define BM 64
#define BN 64
#define BK 32
#define LDA 68

__global__ __launch_bounds__(256) void simred_kernel(
        const float* __restrict__ X, const int* __restrict__ T,
        float* __restrict__ S, float* __restrict__ SAME) {
    __shared__ float As[BK * LDA];
    __shared__ float Bs[BK * LDA];
    __shared__ int   trow[BM], tcol[BN];
    __shared__ float redS[BM], redSame[BM];

    const int tid = threadIdx.x;
    const int tx = tid & 15, ty = tid >> 4;
    const int i0 = blockIdx.x * BM, j0 = blockIdx.y * BN;

    if (tid < BM) {
        trow[tid] = T[i0 + tid];
        tcol[tid] = T[j0 + tid];
        redS[tid] = 0.f;
        redSame[tid] = 0.f;
    }

    float c[4][4] = {};
    for (int kk = 0; kk < EMB; kk += BK) {
        #pragma unroll
        for (int q = 0; q < 2; ++q) {
            int l  = tid * 2 + q;
            int r  = l >> 3;
            int kq = (l & 7) << 2;
            const float4 va = *(const float4*)(X + (size_t)(i0 + r) * EMB + kk + kq);
            As[(kq + 0) * LDA + r] = va.x;
            As[(kq + 1) * LDA + r] = va.y;
            As[(kq + 2) * LDA + r] = va.z;
            As[(kq + 3) * LDA + r] = va.w;
            const float4 vb = *(const float4*)(X + (size_t)(j0 + r) * EMB + kk + kq);
            Bs[(kq + 0) * LDA + r] = vb.x;
            Bs[(kq + 1) * LDA + r] = vb.y;
            Bs[(kq + 2) * LDA + r] = vb.z;
            Bs[(kq + 3) * LDA + r] = vb.w;
        }
        __syncthreads();
        #pragma unroll
        for (int k = 0; k < BK; ++k) {
            float4 a4 = *(const float4*)&As[k * LDA + ty * 4];
            float4 b4 = *(const float4*)&Bs[k * LDA + tx * 4];
            float a[4] = {a4.x, a4.y, a4.z, a4.w};
            float b[4] = {b4.x, b4.y, b4.z, b4.w};
            #pragma unroll
            for (int i = 0; i < 4; ++i)
                #pragma unroll
                for (int j = 0; j < 4; ++j)
                    c[i][j] = fmaf(a[i], b[j], c[i][j]);
        }
        __syncthreads();
    }

    #pragma unroll
    for (int i = 0; i < 4; ++i) {
        int r = ty * 4 + i;
        int tr = trow[r];
        float s = 0.f, sm = 0.f;
        #pragma unroll
        for (int j = 0; j < 4; ++j) {
            float v = c[i][j];
            s += v;
            if (tcol[tx * 4 + j] == tr) sm += v;
        }
        atomicAdd(&redS[r], s);
        atomicAdd(&redSame[r], sm);
    }
    __syncthreads();
    if (tid < BM) {
        atomicAdd(&S[i0 + tid],    redS[tid]);
        atomicAdd(&SAME[i0 + tid], redSame[tid]);
    }
}

// ---------------- fallback loss (one block per row) ----------------
__global__ __launch_bounds__(128) void loss_kernel(
        const float* __restrict__ X, const int* __restrict__ T,
        const float* __restrict__ K, const float* __restrict__ colinv,
        double* __restrict__ acc) {
    const int row = blockIdx.x;
    const int tid = threadIdx.x;
    __shared__ float xs[EMB];
    *(float4*)&xs[tid * 4] = *(const float4*)&X[(size_t)row * EMB + tid * 4];
    __syncthreads();

    const int tgt = T[row];
    const int c = tid;
    float logit = -1e30f;
    if (c < NCLS) {
        float d = 0.f;
        #pragma unroll 4
        for (int k = 0; k < EMB; ++k) d = fmaf(K[k * NCLS + c], xs[k], d);
        float cosv = d * colinv[c];
        cosv = fminf(1.f, fmaxf(-1.f, cosv));
        logit = (cosv - (c == tgt ? BETA_F : 0.f)) * ALPHA_F;
    }

    __shared__ float rv[128];
    __shared__ int   ri[128];
    __shared__ float Lt;
    if (c == tgt) Lt = logit;

    rv[tid] = logit;
    __syncthreads();
    #pragma unroll
    for (int s = 64; s > 0; s >>= 1) {
        if (tid < s) rv[tid] = fmaxf(rv[tid], rv[tid + s]);
        __syncthreads();
    }
    const float m = rv[0];
    __syncthreads();

    rv[tid] = (c < NCLS) ? expf(logit - m) : 0.f;
    __syncthreads();
    #pragma unroll
    for (int s = 64; s > 0; s >>= 1) {
        if (tid < s) rv[tid] += rv[tid + s];
        __syncthreads();
    }
    const float lse = m + logf(rv[0]);
    __syncthreads();

    rv[tid] = logit;
    ri[tid] = (c < NCLS) ? c : 0x7fffffff;
    __syncthreads();
    #pragma unroll
    for (int s = 64; s > 0; s >>= 1) {
        if (tid < s) {
            float vo = rv[tid + s]; int io = ri[tid + s];
            if (vo > rv[tid] || (vo == rv[tid] && io < ri[tid])) { rv[tid] = vo; ri[tid] = io; }
        }
        __syncthreads();
    }

    if (tid == 0) {
        float loss_i = lse - Lt;
        atomicAdd(&acc[0], (double)loss_i);
        atomicAdd(&acc[1], (ri[0] == tgt) ? 1.0 : 0.0);
    }
}

// ---------------- per-row finalize: pos/neg means ----------------
__global__ void finalize_kernel(
        const float* __restrict__ X, const int* __restrict__ T,
        const int* __restrict__ hist, const float* __restrict__ S,
        const float* __restrict__ SAME, double* __restrict__ acc) {
    int r = blockIdx.x * blockDim.x + threadIdx.x;
    if (r >= NROWS) return;
    const float* x = X + (size_t)r * EMB;
    double d = 0.0;
    for (int k = 0; k < EMB; ++k) d = fma((double)x[k], (double)x[k], d);
    int h = hist[T[r]];
    float same = SAME[r];
    float pos_sum; int pos_cnt;
    if (d < 1.0) {
        pos_sum = same;
        pos_cnt = h;
    } else {
        pos_sum = same - (float)d;
        pos_cnt = h - 1;
    }
    float neg_sum = S[r] - same;
    int   neg_cnt = NROWS - h;
    atomicAdd(&acc[2], (double)(pos_sum / (float)pos_cnt));
    atomicAdd(&acc[3], (double)(neg_sum / (float)neg_cnt));
}

__global__ void out_kernel(const double* __restrict__ acc, float* __restrict__ out) {
    if (threadIdx.x == 0) {
        out[0] = (float)(acc[0] / NROWS);
        out[1] = (float)(acc[1] / NROWS);
        out[2] = (float)(acc[2] / NROWS);
        out[3] = (float)(acc[3] / NROWS);
    }
}

extern "C" void kernel_launch(void* const* d_in, const int* in_sizes, int n_in,
                              void* d_out, int out_size, void* d_ws, size_t ws_size,
                              hipStream_t stream) {
    const float* X = (const float*)d_in[0];   // [8192, 512]
    const int*   T = (const int*)d_in[1];     // [8192]
    const float* K = (const float*)d_in[2];   // [512, 98]
    float* out = (float*)d_out;               // 4 scalars

    const size_t XB_BYTES  = (size_t)NROWS * EMB * sizeof(unsigned short);  // 8 MB
    const size_t KBT_BYTES = (size_t)NCPAD * EMB * sizeof(unsigned short);  // 128 KB
    const size_t MISC_BYTES = sizeof(double) * 4 + sizeof(int) * NCLS
                            + sizeof(float) * (NCLS + 2 * NROWS);

    if (ws_size >= XB_BYTES + KBT_BYTES + MISC_BYTES + 256) {
        // fast path: bf16 MFMA for sim reduction AND logits
        unsigned short* Xb  = (unsigned short*)d_ws;
        unsigned short* KbT = (unsigned short*)((char*)d_ws + XB_BYTES);
        char* misc = (char*)d_ws + XB_BYTES + KBT_BYTES;
        double* acc    = (double*)misc;
        int*    hist   = (int*)(acc + 4);
        float*  colinv = (float*)(hist + NCLS);
        float*  S      = colinv + NCLS;
        float*  SAME   = S + NROWS;

        hipMemsetAsync(misc, 0, MISC_BYTES, stream);
        tobf16_kernel<<<(NROWS * EMB / 8 + 255) / 256, 256, 0, stream>>>(X, Xb);
        kprep_kernel<<<NCPAD, 64, 0, stream>>>(K, KbT);
        hist_kernel<<<(NROWS + 255) / 256, 256, 0, stream>>>(T, hist);
        simred_mfma<<<dim3(NROWS / TBM, NROWS / TBN), 256, 0, stream>>>(Xb, T, S, SAME);
        logits_kernel<<<NROWS / 16, 64, 0, stream>>>(Xb, KbT, T, acc);
        finalize_kernel<<<(NROWS + 255) / 256, 256, 0, stream>>>(X, T, hist, S, SAME, acc);
        out_kernel<<<1, 64, 0, stream>>>(acc, out);
    } else if (ws_size >= XB_BYTES + MISC_BYTES + 256) {
        // mid path: bf16 sim, f32 loss
        unsigned short* Xb = (unsigned short*)d_ws;
        char* misc = (char*)d_ws + XB_BYTES;
        double* acc    = (double*)misc;
        int*    hist   = (int*)(acc + 4);
        float*  colinv = (float*)(hist + NCLS);
        float*  S      = colinv + NCLS;
        float*  SAME   = S + NROWS;

        hipMemsetAsync(misc, 0, MISC_BYTES, stream);
        tobf16_kernel<<<(NROWS * EMB / 8 + 255) / 256, 256, 0, stream>>>(X, Xb);
        hist_kernel<<<(NROWS + 255) / 256, 256, 0, stream>>>(T, hist);
        colnorm_kernel<<<NCLS, 64, 0, stream>>>(K, colinv);
        simred_mfma<<<dim3(NROWS / TBM, NROWS / TBN), 256, 0, stream>>>(Xb, T, S, SAME);
        loss_kernel<<<NROWS, 128, 0, stream>>>(X, T, K, colinv, acc);
        finalize_kernel<<<(NROWS + 255) / 256, 256, 0, stream>>>(X, T, hist, S, SAME, acc);
        out_kernel<<<1, 64, 0, stream>>>(acc, out);
    } else {
        // fallback: f32 path
        double* acc    = (double*)d_ws;
        int*    hist   = (int*)(acc + 4);
        float*  colinv = (float*)(hist + NCLS);
        float*  S      = colinv + NCLS;
        float*  SAME   = S + NROWS;

        hipMemsetAsync(d_ws, 0, MISC_BYTES, stream);
        hist_kernel<<<(NROWS + 255) / 256, 256, 0, stream>>>(T, hist);
        colnorm_kernel<<<NCLS, 64, 0, stream>>>(K, colinv);
        simred_kernel<<<dim3(NROWS / BM, NROWS / BN), 256, 0, stream>>>(X, T, S, SAME);
        loss_kernel<<<NROWS, 128, 0, stream>>>(X, T, K, colinv, acc);
        finalize_kernel<<<(NROWS + 255) / 256, 256, 0, stream>>>(X, T, hist, S, SAME, acc);
        out_kernel<<<1, 64, 0, stream>>>(acc, out);
    }
}

// Round 4
// 93.280 us; speedup vs baseline: 14.1172x; 2.2367x over previous
//
#include <hip/hip_runtime.h>
#include <hip/hip_bf16.h>

typedef __attribute__((ext_vector_type(8))) short bf16x8;
typedef __attribute__((ext_vector_type(4))) float f32x4;

#define NROWS 8192
#define EMB   512
#define NCLS  98
#define NCPAD 128
#define ALPHA_F 10.0f
#define BETA_F  2.0f

__device__ __forceinline__ unsigned short f2bf(float x) {
    unsigned u = __builtin_bit_cast(unsigned, x);
    u += 0x7FFF + ((u >> 16) & 1);
    return (unsigned short)(u >> 16);
}

// ---------------- class histogram ----------------
__global__ void hist_kernel(const int* __restrict__ t, int* __restrict__ hist) {
    int i = blockIdx.x * blockDim.x + threadIdx.x;
    if (i < NROWS) atomicAdd(&hist[t[i]], 1);
}

// ---------------- KbT[c][k] = bf16( K[k][c] / ||K[:,c]|| ), c in [0,128) padded ----------------
__global__ __launch_bounds__(64) void kprep_kernel(const float* __restrict__ K,
                                                   unsigned short* __restrict__ KbT) {
    int c = blockIdx.x;      // 0..127
    int t = threadIdx.x;     // 0..63
    if (c < NCLS) {
        float v[8]; float s = 0.f;
        #pragma unroll
        for (int q = 0; q < 8; ++q) {
            float x = K[(size_t)(t + q * 64) * NCLS + c];
            v[q] = x; s = fmaf(x, x, s);
        }
        #pragma unroll
        for (int d = 32; d > 0; d >>= 1) s += __shfl_xor(s, d);
        float inv = 1.0f / sqrtf(s);
        #pragma unroll
        for (int q = 0; q < 8; ++q)
            KbT[(size_t)c * EMB + t + q * 64] = f2bf(v[q] * inv);
    } else {
        #pragma unroll
        for (int q = 0; q < 8; ++q)
            KbT[(size_t)c * EMB + t + q * 64] = 0;
    }
}

// ---------------- class-sum vectors: V[c][k] = sum_{rows r: T[r]=c} X[r][k] ----------------
#define CS_DIMS 64
#define CS_ROWS 256
__global__ __launch_bounds__(256) void classsum_kernel(
        const float* __restrict__ X, const int* __restrict__ T,
        float* __restrict__ V) {
    __shared__ float Vloc[NCLS * CS_DIMS];   // 98*64 floats = 24.5 KB
    const int tid = threadIdx.x;
    for (int i = tid; i < NCLS * CS_DIMS; i += 256) Vloc[i] = 0.f;
    __syncthreads();

    const int d0 = blockIdx.x * CS_DIMS;     // 8 dim-chunks
    const int r0 = blockIdx.y * CS_ROWS;     // 32 row-chunks
    const int lane = tid & 63, w = tid >> 6;

    for (int r = w; r < CS_ROWS; r += 4) {
        int row = r0 + r;
        int cls = T[row];
        float x = X[(size_t)row * EMB + d0 + lane];
        atomicAdd(&Vloc[cls * CS_DIMS + lane], x);
    }
    __syncthreads();
    for (int i = tid; i < NCLS * CS_DIMS; i += 256) {
        int c = i >> 6, d = i & 63;
        atomicAdd(&V[(size_t)c * EMB + d0 + d], Vloc[i]);
    }
}

// ---------------- usum[k] = sum_c V[c][k] ----------------
__global__ __launch_bounds__(64) void usum_kernel(const float* __restrict__ V,
                                                  float* __restrict__ usum) {
    int k = blockIdx.x * 64 + threadIdx.x;   // 512 total
    float s = 0.f;
    for (int c = 0; c < NCLS; ++c) s += V[(size_t)c * EMB + k];
    usum[k] = s;
}

// ---------------- MFMA logits + in-register softmax/argmax/loss ----------------
// one wave per 16 rows; reads X f32 and converts inline; KbT is [128][512] bf16
__global__ __launch_bounds__(64) void logits_kernel(
        const float* __restrict__ X, const unsigned short* __restrict__ KbT,
        const int* __restrict__ T, double* __restrict__ acc) {
    const int row0 = blockIdx.x * 16;
    const int lane = threadIdx.x;
    const int c0 = lane & 15, g = lane >> 4;

    f32x4 av[8] = {};
    for (int kk = 0; kk < EMB; kk += 32) {
        const float* xp = &X[(size_t)(row0 + c0) * EMB + kk + g * 8];
        float4 x0 = *(const float4*)xp, x1 = *(const float4*)(xp + 4);
        float xf[8] = {x0.x, x0.y, x0.z, x0.w, x1.x, x1.y, x1.z, x1.w};
        bf16x8 a;
        #pragma unroll
        for (int j = 0; j < 8; ++j) a[j] = (short)f2bf(xf[j]);
        #pragma unroll
        for (int f = 0; f < 8; ++f) {
            bf16x8 b = *(const bf16x8*)&KbT[(size_t)(f * 16 + c0) * EMB + kk + g * 8];
            av[f] = __builtin_amdgcn_mfma_f32_16x16x32_bf16(a, b, av[f], 0, 0, 0);
        }
    }

    float lossacc = 0.f, pracc = 0.f;
    #pragma unroll
    for (int r = 0; r < 4; ++r) {
        const int row = row0 + g * 4 + r;
        const int tgt = T[row];
        float vals[8];
        float m = -1e30f;
        #pragma unroll
        for (int f = 0; f < 8; ++f) {
            int col = f * 16 + c0;
            float cosv = fminf(1.f, fmaxf(-1.f, av[f][r]));
            float logit = (cosv - (col == tgt ? BETA_F : 0.f)) * ALPHA_F;
            if (col >= NCLS) logit = -1e30f;
            vals[f] = logit;
            m = fmaxf(m, logit);
        }
        #pragma unroll
        for (int d = 1; d < 16; d <<= 1) m = fmaxf(m, __shfl_xor(m, d));

        float se = 0.f, tval = -1e30f;
        float bv = -1e30f; int bi = 0x7fffffff;
        #pragma unroll
        for (int f = 0; f < 8; ++f) {
            int col = f * 16 + c0;
            se += __expf(vals[f] - m) * (col < NCLS ? 1.f : 0.f);
            if (col == tgt) tval = vals[f];
            if (vals[f] > bv) { bv = vals[f]; bi = col; }
        }
        #pragma unroll
        for (int d = 1; d < 16; d <<= 1) {
            se += __shfl_xor(se, d);
            tval = fmaxf(tval, __shfl_xor(tval, d));
            float ov = __shfl_xor(bv, d); int oi = __shfl_xor(bi, d);
            if (ov > bv || (ov == bv && oi < bi)) { bv = ov; bi = oi; }
        }
        if (c0 == 0) {
            lossacc += (m + logf(se)) - tval;
            pracc += (bi == tgt) ? 1.f : 0.f;
        }
    }
    lossacc += __shfl_xor(lossacc, 16); lossacc += __shfl_xor(lossacc, 32);
    pracc   += __shfl_xor(pracc, 16);   pracc   += __shfl_xor(pracc, 32);
    if (lane == 0) {
        atomicAdd(&acc[0], (double)lossacc);
        atomicAdd(&acc[1], (double)pracc);
    }
}

// ---------------- per-row finalize: s = x.u, same = x.V[t], d = ||x||^2 (f64) ----------------
__global__ __launch_bounds__(256) void rowfin_kernel(
        const float* __restrict__ X, const int* __restrict__ T,
        const int* __restrict__ hist, const float* __restrict__ V,
        const float* __restrict__ usum, double* __restrict__ posneg) {
    __shared__ double red[8];
    const int w = threadIdx.x >> 6, lane = threadIdx.x & 63;
    const int row = blockIdx.x * 4 + w;
    const int t = T[row];
    const float* x = X + (size_t)row * EMB;
    const float* v = V + (size_t)t * EMB;

    float s = 0.f, sm = 0.f; double d = 0.0;
    #pragma unroll
    for (int q = 0; q < 2; ++q) {
        float4 xv = *(const float4*)(x + lane * 8 + q * 4);
        float4 uv = *(const float4*)(usum + lane * 8 + q * 4);
        float4 vv = *(const float4*)(v + lane * 8 + q * 4);
        s  = fmaf(xv.x, uv.x, s);  s  = fmaf(xv.y, uv.y, s);
        s  = fmaf(xv.z, uv.z, s);  s  = fmaf(xv.w, uv.w, s);
        sm = fmaf(xv.x, vv.x, sm); sm = fmaf(xv.y, vv.y, sm);
        sm = fmaf(xv.z, vv.z, sm); sm = fmaf(xv.w, vv.w, sm);
        d  = fma((double)xv.x, (double)xv.x, d);
        d  = fma((double)xv.y, (double)xv.y, d);
        d  = fma((double)xv.z, (double)xv.z, d);
        d  = fma((double)xv.w, (double)xv.w, d);
    }
    #pragma unroll
    for (int m = 1; m < 64; m <<= 1) {
        s  += __shfl_xor(s, m);
        sm += __shfl_xor(sm, m);
        d  += __shfl_xor(d, m);
    }
    if (lane == 0) {
        int h = hist[t];
        float pos_sum; int pos_cnt;
        if (d < 1.0) { pos_sum = sm;            pos_cnt = h;     }
        else         { pos_sum = sm - (float)d; pos_cnt = h - 1; }
        float neg_sum = s - sm;
        int   neg_cnt = NROWS - h;
        red[w * 2]     = (double)(pos_sum / (float)pos_cnt);
        red[w * 2 + 1] = (double)(neg_sum / (float)neg_cnt);
    }
    __syncthreads();
    if (threadIdx.x == 0) {
        double p = red[0] + red[2] + red[4] + red[6];
        double n = red[1] + red[3] + red[5] + red[7];
        int b = (blockIdx.x & 63) * 2;
        atomicAdd(&posneg[b],     p);
        atomicAdd(&posneg[b + 1], n);
    }
}

__global__ void out2_kernel(const double* __restrict__ acc,
                            const double* __restrict__ posneg,
                            float* __restrict__ out) {
    if (threadIdx.x == 0) {
        double p = 0.0, n = 0.0;
        for (int i = 0; i < 64; ++i) { p += posneg[i * 2]; n += posneg[i * 2 + 1]; }
        out[0] = (float)(acc[0] / NROWS);
        out[1] = (float)(acc[1] / NROWS);
        out[2] = (float)(p / NROWS);
        out[3] = (float)(n / NROWS);
    }
}

// ================= fallback f32 path (tiny workspace) =================
#define BM 64
#define BN 64
#define BK 32
#define LDA 68

__global__ void colnorm_kernel(const float* __restrict__ K, float* __restrict__ colinv) {
    int c = blockIdx.x;
    float s = 0.f;
    for (int k = threadIdx.x; k < EMB; k += 64) {
        float v = K[k * NCLS + c];
        s = fmaf(v, v, s);
    }
    #pragma unroll
    for (int off = 32; off > 0; off >>= 1) s += __shfl_down(s, off);
    if (threadIdx.x == 0) colinv[c] = 1.0f / sqrtf(s);
}

__global__ __launch_bounds__(256) void simred_kernel(
        const float* __restrict__ X, const int* __restrict__ T,
        float* __restrict__ S, float* __restrict__ SAME) {
    __shared__ float As[BK * LDA];
    __shared__ float Bs[BK * LDA];
    __shared__ int   trow[BM], tcol[BN];
    __shared__ float redS[BM], redSame[BM];

    const int tid = threadIdx.x;
    const int tx = tid & 15, ty = tid >> 4;
    const int i0 = blockIdx.x * BM, j0 = blockIdx.y * BN;

    if (tid < BM) {
        trow[tid] = T[i0 + tid];
        tcol[tid] = T[j0 + tid];
        redS[tid] = 0.f;
        redSame[tid] = 0.f;
    }

    float c[4][4] = {};
    for (int kk = 0; kk < EMB; kk += BK) {
        #pragma unroll
        for (int q = 0; q < 2; ++q) {
            int l  = tid * 2 + q;
            int r  = l >> 3;
            int kq = (l & 7) << 2;
            const float4 va = *(const float4*)(X + (size_t)(i0 + r) * EMB + kk + kq);
            As[(kq + 0) * LDA + r] = va.x;
            As[(kq + 1) * LDA + r] = va.y;
            As[(kq + 2) * LDA + r] = va.z;
            As[(kq + 3) * LDA + r] = va.w;
            const float4 vb = *(const float4*)(X + (size_t)(j0 + r) * EMB + kk + kq);
            Bs[(kq + 0) * LDA + r] = vb.x;
            Bs[(kq + 1) * LDA + r] = vb.y;
            Bs[(kq + 2) * LDA + r] = vb.z;
            Bs[(kq + 3) * LDA + r] = vb.w;
        }
        __syncthreads();
        #pragma unroll
        for (int k = 0; k < BK; ++k) {
            float4 a4 = *(const float4*)&As[k * LDA + ty * 4];
            float4 b4 = *(const float4*)&Bs[k * LDA + tx * 4];
            float a[4] = {a4.x, a4.y, a4.z, a4.w};
            float b[4] = {b4.x, b4.y, b4.z, b4.w};
            #pragma unroll
            for (int i = 0; i < 4; ++i)
                #pragma unroll
                for (int j = 0; j < 4; ++j)
                    c[i][j] = fmaf(a[i], b[j], c[i][j]);
        }
        __syncthreads();
    }

    #pragma unroll
    for (int i = 0; i < 4; ++i) {
        int r = ty * 4 + i;
        int tr = trow[r];
        float s = 0.f, sm = 0.f;
        #pragma unroll
        for (int j = 0; j < 4; ++j) {
            float v = c[i][j];
            s += v;
            if (tcol[tx * 4 + j] == tr) sm += v;
        }
        atomicAdd(&redS[r], s);
        atomicAdd(&redSame[r], sm);
    }
    __syncthreads();
    if (tid < BM) {
        atomicAdd(&S[i0 + tid],    redS[tid]);
        atomicAdd(&SAME[i0 + tid], redSame[tid]);
    }
}

__global__ __launch_bounds__(128) void loss_kernel(
        const float* __restrict__ X, const int* __restrict__ T,
        const float* __restrict__ K, const float* __restrict__ colinv,
        double* __restrict__ acc) {
    const int row = blockIdx.x;
    const int tid = threadIdx.x;
    __shared__ float xs[EMB];
    *(float4*)&xs[tid * 4] = *(const float4*)&X[(size_t)row * EMB + tid * 4];
    __syncthreads();

    const int tgt = T[row];
    const int c = tid;
    float logit = -1e30f;
    if (c < NCLS) {
        float d = 0.f;
        #pragma unroll 4
        for (int k = 0; k < EMB; ++k) d = fmaf(K[k * NCLS + c], xs[k], d);
        float cosv = d * colinv[c];
        cosv = fminf(1.f, fmaxf(-1.f, cosv));
        logit = (cosv - (c == tgt ? BETA_F : 0.f)) * ALPHA_F;
    }

    __shared__ float rv[128];
    __shared__ int   ri[128];
    __shared__ float Lt;
    if (c == tgt) Lt = logit;

    rv[tid] = logit;
    __syncthreads();
    #pragma unroll
    for (int s = 64; s > 0; s >>= 1) {
        if (tid < s) rv[tid] = fmaxf(rv[tid], rv[tid + s]);
        __syncthreads();
    }
    const float m = rv[0];
    __syncthreads();

    rv[tid] = (c < NCLS) ? expf(logit - m) : 0.f;
    __syncthreads();
    #pragma unroll
    for (int s = 64; s > 0; s >>= 1) {
        if (tid < s) rv[tid] += rv[tid + s];
        __syncthreads();
    }
    const float lse = m + logf(rv[0]);
    __syncthreads();

    rv[tid] = logit;
    ri[tid] = (c < NCLS) ? c : 0x7fffffff;
    __syncthreads();
    #pragma unroll
    for (int s = 64; s > 0; s >>= 1) {
        if (tid < s) {
            float vo = rv[tid + s]; int io = ri[tid + s];
            if (vo > rv[tid] || (vo == rv[tid] && io < ri[tid])) { rv[tid] = vo; ri[tid] = io; }
        }
        __syncthreads();
    }

    if (tid == 0) {
        float loss_i = lse - Lt;
        atomicAdd(&acc[0], (double)loss_i);
        atomicAdd(&acc[1], (ri[0] == tgt) ? 1.0 : 0.0);
    }
}

__global__ void finalize_kernel(
        const float* __restrict__ X, const int* __restrict__ T,
        const int* __restrict__ hist, const float* __restrict__ S,
        const float* __restrict__ SAME, double* __restrict__ acc) {
    int r = blockIdx.x * blockDim.x + threadIdx.x;
    if (r >= NROWS) return;
    const float* x = X + (size_t)r * EMB;
    double d = 0.0;
    for (int k = 0; k < EMB; ++k) d = fma((double)x[k], (double)x[k], d);
    int h = hist[T[r]];
    float same = SAME[r];
    float pos_sum; int pos_cnt;
    if (d < 1.0) { pos_sum = same;            pos_cnt = h;     }
    else         { pos_sum = same - (float)d; pos_cnt = h - 1; }
    float neg_sum = S[r] - same;
    int   neg_cnt = NROWS - h;
    atomicAdd(&acc[2], (double)(pos_sum / (float)pos_cnt));
    atomicAdd(&acc[3], (double)(neg_sum / (float)neg_cnt));
}

__global__ void out_kernel(const double* __restrict__ acc, float* __restrict__ out) {
    if (threadIdx.x == 0) {
        out[0] = (float)(acc[0] / NROWS);
        out[1] = (float)(acc[1] / NROWS);
        out[2] = (float)(acc[2] / NROWS);
        out[3] = (float)(acc[3] / NROWS);
    }
}

extern "C" void kernel_launch(void* const* d_in, const int* in_sizes, int n_in,
                              void* d_out, int out_size, void* d_ws, size_t ws_size,
                              hipStream_t stream) {
    const float* X = (const float*)d_in[0];   // [8192, 512]
    const int*   T = (const int*)d_in[1];     // [8192]
    const float* K = (const float*)d_in[2];   // [512, 98]
    float* out = (float*)d_out;               // 4 scalars

    const size_t KBT_BYTES = (size_t)NCPAD * EMB * sizeof(unsigned short);  // 128 KB
    // misc block: acc(4 dbl) + posneg(128 dbl) + hist(100 int) + V(98*512 f) + usum(512 f)
    const size_t MISC_BYTES = 4 * 8 + 128 * 8 + 100 * 4
                            + (size_t)(NCLS * EMB + EMB) * 4;

    if (ws_size >= KBT_BYTES + MISC_BYTES + 256) {
        // fast path: class-sum factorization + MFMA logits
        unsigned short* KbT = (unsigned short*)d_ws;
        char* misc = (char*)d_ws + KBT_BYTES;
        double* acc    = (double*)misc;
        double* posneg = acc + 4;
        int*    hist   = (int*)(posneg + 128);
        float*  V      = (float*)(hist + 100);
        float*  usum   = V + (size_t)NCLS * EMB;

        hipMemsetAsync(misc, 0, MISC_BYTES, stream);
        kprep_kernel<<<NCPAD, 64, 0, stream>>>(K, KbT);
        hist_kernel<<<(NROWS + 255) / 256, 256, 0, stream>>>(T, hist);
        classsum_kernel<<<dim3(EMB / CS_DIMS, NROWS / CS_ROWS), 256, 0, stream>>>(X, T, V);
        usum_kernel<<<EMB / 64, 64, 0, stream>>>(V, usum);
        logits_kernel<<<NROWS / 16, 64, 0, stream>>>(X, KbT, T, acc);
        rowfin_kernel<<<NROWS / 4, 256, 0, stream>>>(X, T, hist, V, usum, posneg);
        out2_kernel<<<1, 64, 0, stream>>>(acc, posneg, out);
    } else {
        // fallback: f32 path (small workspace)
        const size_t FB_BYTES = sizeof(double) * 4 + sizeof(int) * NCLS
                              + sizeof(float) * (NCLS + 2 * NROWS);
        double* acc    = (double*)d_ws;
        int*    hist   = (int*)(acc + 4);
        float*  colinv = (float*)(hist + NCLS);
        float*  S      = colinv + NCLS;
        float*  SAME   = S + NROWS;

        hipMemsetAsync(d_ws, 0, FB_BYTES, stream);
        hist_kernel<<<(NROWS + 255) / 256, 256, 0, stream>>>(T, hist);
        colnorm_kernel<<<NCLS, 64, 0, stream>>>(K, colinv);
        simred_kernel<<<dim3(NROWS / BM, NROWS / BN), 256, 0, stream>>>(X, T, S, SAME);
        loss_kernel<<<NROWS, 128, 0, stream>>>(X, T, K, colinv, acc);
        finalize_kernel<<<(NROWS + 255) / 256, 256, 0, stream>>>(X, T, hist, S, SAME, acc);
        out_kernel<<<1, 64, 0, stream>>>(acc, out);
    }
}